// Round 2
// baseline (961.453 us; speedup 1.0000x reference)
//
#include <hip/hip_runtime.h>
#include <hip/hip_bf16.h>

// RecurrentCrossLinearAttention: N=16, S=4096, H=16, D=64, M=64, fp32.
// Round 2: split S into 2 halves -> 512 blocks (2 blocks/CU) for barrier
// overlap + memory-level parallelism. Partial S_state/Z go to d_ws; a small
// reduce kernel sums halves and computes V_out/Z/S_state outputs.

#define S_LEN  4096
#define NHEAD  16
#define DDIM   64
#define MDIM   64
#define CHUNK  64
#define NTH    512
#define SPLIT  2
#define SHALF  (S_LEN / SPLIT)
#define NCHUNK_H (SHALF / CHUNK)          // 32 chunks per half

#define OUT_SOFF  16384                   // N*H*M
#define OUT_ZOFF  (16384 + 1048576)       // + N*H*M*D

#define WS_ROW    (MDIM * DDIM + DDIM)    // 4160 floats per partial
#define WS_NEED   ((size_t)256 * SPLIT * WS_ROW * sizeof(float))

__device__ __forceinline__ float elup1(float x) {
    return x > 0.0f ? x + 1.0f : __expf(x);
}

// ---------------- main partial-accumulation kernel (split-S) ----------------
__global__ __launch_bounds__(NTH, 4)
void rcla_partial(const float* __restrict__ keys,
                  const float* __restrict__ values,
                  const float* __restrict__ kmask,
                  float* __restrict__ ws)
{
    __shared__ float Ks[CHUNK * DDIM];    // 16 KB (elu'd, masked K)
    __shared__ float Vs[CHUNK * MDIM];    // 16 KB (raw V)
    __shared__ float buf[MDIM * DDIM];    // 16 KB merge buffer
    __shared__ float zbuf[DDIM];

    const int t    = threadIdx.x;
    const int pair = blockIdx.x >> 1;     // n*16 + h
    const int half = blockIdx.x & 1;
    const int nIdx = pair >> 4;
    const int hIdx = pair & 15;
    const int wave = t >> 6;
    const int lane = t & 63;
    const int mgrp = lane >> 3;
    const int dgrp = lane & 7;
    const int m0 = mgrp * 8;
    const int d0 = dgrp * 8;

    const int srow0 = t >> 4;             // 0..31
    const int srow1 = srow0 + 32;
    const int scol  = (t & 15) * 4;

    const size_t rowStride = (size_t)NHEAD * DDIM;   // 1024 floats
    const size_t base = ((size_t)nIdx * S_LEN * NHEAD + hIdx) * DDIM
                      + (size_t)half * SHALF * rowStride;
    const float* kp0 = keys   + base + (size_t)srow0 * rowStride + scol;
    const float* kp1 = keys   + base + (size_t)srow1 * rowStride + scol;
    const float* vp0 = values + base + (size_t)srow0 * rowStride + scol;
    const float* vp1 = values + base + (size_t)srow1 * rowStride + scol;
    const float* mp  = kmask + (size_t)nIdx * S_LEN + half * SHALF + srow0;

    float acc[8][8];
    float zz[8];
#pragma unroll
    for (int i = 0; i < 8; ++i) {
        zz[i] = 0.0f;
#pragma unroll
        for (int j = 0; j < 8; ++j) acc[i][j] = 0.0f;
    }

    float4 ka = *(const float4*)kp0;
    float4 kb = *(const float4*)kp1;
    float4 va = *(const float4*)vp0;
    float4 vb = *(const float4*)vp1;
    float mk0 = mp[0], mk1 = mp[32];

    const int rbase = wave * 8;
    const size_t step = (size_t)CHUNK * rowStride;

    for (int c = 0; c < NCHUNK_H; ++c) {
        float4 k0, k1;
        k0.x = elup1(ka.x) * mk0;  k0.y = elup1(ka.y) * mk0;
        k0.z = elup1(ka.z) * mk0;  k0.w = elup1(ka.w) * mk0;
        k1.x = elup1(kb.x) * mk1;  k1.y = elup1(kb.y) * mk1;
        k1.z = elup1(kb.z) * mk1;  k1.w = elup1(kb.w) * mk1;
        float4 v0 = va, v1 = vb;

        __syncthreads();
        *(float4*)&Ks[srow0 * DDIM + scol] = k0;
        *(float4*)&Ks[srow1 * DDIM + scol] = k1;
        *(float4*)&Vs[srow0 * MDIM + scol] = v0;
        *(float4*)&Vs[srow1 * MDIM + scol] = v1;
        __syncthreads();

        if (c + 1 < NCHUNK_H) {
            kp0 += step; kp1 += step; vp0 += step; vp1 += step; mp += CHUNK;
            ka = *(const float4*)kp0;
            kb = *(const float4*)kp1;
            va = *(const float4*)vp0;
            vb = *(const float4*)vp1;
            mk0 = mp[0]; mk1 = mp[32];
        }

#pragma unroll
        for (int r = 0; r < 8; ++r) {
            const int row = rbase + r;
            const float4 kk0 = *(const float4*)&Ks[row * DDIM + d0];
            const float4 kk1 = *(const float4*)&Ks[row * DDIM + d0 + 4];
            const float4 vv0 = *(const float4*)&Vs[row * MDIM + m0];
            const float4 vv1 = *(const float4*)&Vs[row * MDIM + m0 + 4];
            const float kv[8] = {kk0.x, kk0.y, kk0.z, kk0.w, kk1.x, kk1.y, kk1.z, kk1.w};
            const float vm[8] = {vv0.x, vv0.y, vv0.z, vv0.w, vv1.x, vv1.y, vv1.z, vv1.w};
#pragma unroll
            for (int mi = 0; mi < 8; ++mi)
#pragma unroll
                for (int di = 0; di < 8; ++di)
                    acc[mi][di] = fmaf(vm[mi], kv[di], acc[mi][di]);
#pragma unroll
            for (int di = 0; di < 8; ++di) zz[di] += kv[di];
        }
    }

    // cross-wave merge through LDS
    for (int w = 0; w < 8; ++w) {
        if (wave == w) {
#pragma unroll
            for (int mi = 0; mi < 8; ++mi) {
                float4* row = (float4*)&buf[(m0 + mi) * DDIM + d0];
                if (w == 0) {
                    row[0] = make_float4(acc[mi][0], acc[mi][1], acc[mi][2], acc[mi][3]);
                    row[1] = make_float4(acc[mi][4], acc[mi][5], acc[mi][6], acc[mi][7]);
                } else {
                    float4 a = row[0], b = row[1];
                    a.x += acc[mi][0]; a.y += acc[mi][1]; a.z += acc[mi][2]; a.w += acc[mi][3];
                    b.x += acc[mi][4]; b.y += acc[mi][5]; b.z += acc[mi][6]; b.w += acc[mi][7];
                    row[0] = a; row[1] = b;
                }
            }
            if (mgrp == 0) {
#pragma unroll
                for (int i = 0; i < 8; ++i) {
                    if (w == 0) zbuf[d0 + i] = zz[i];
                    else        zbuf[d0 + i] += zz[i];
                }
            }
        }
        __syncthreads();
    }

    // write partials: [blockIdx.x][4096 S + 64 z]
    float* wrow = ws + (size_t)blockIdx.x * WS_ROW;
    {
        const int row = t >> 3;
        const int col = (t & 7) * 8;
        float* dst = wrow + row * DDIM + col;
        *(float4*)dst       = *(float4*)&buf[row * DDIM + col];
        *((float4*)dst + 1) = *(float4*)&buf[row * DDIM + col + 4];
    }
    if (t < DDIM) wrow[MDIM * DDIM + t] = zbuf[t];
}

// ---------------- reduce + epilogue kernel ----------------
__global__ __launch_bounds__(256)
void rcla_reduce(const float* __restrict__ query,
                 const float* __restrict__ ws,
                 float* __restrict__ out)
{
    __shared__ float S[MDIM * DDIM];
    __shared__ float zb[DDIM];
    __shared__ float qb[DDIM];

    const int p = blockIdx.x;             // pair
    const int t = threadIdx.x;
    const float* a = ws + (size_t)(2 * p) * WS_ROW;
    const float* b = ws + (size_t)(2 * p + 1) * WS_ROW;

    const int i0 = t * 16;
#pragma unroll
    for (int j = 0; j < 16; j += 4) {
        float4 x = *(const float4*)&a[i0 + j];
        const float4 y = *(const float4*)&b[i0 + j];
        x.x += y.x; x.y += y.y; x.z += y.z; x.w += y.w;
        *(float4*)&S[i0 + j] = x;
        *(float4*)&out[OUT_SOFF + (size_t)p * (MDIM * DDIM) + i0 + j] = x;
    }
    if (t < DDIM) {
        const float zv = a[MDIM * DDIM + t] + b[MDIM * DDIM + t];
        zb[t] = zv;
        out[OUT_ZOFF + (size_t)p * DDIM + t] = zv;
        qb[t] = elup1(query[(size_t)p * DDIM + t]);
    }
    __syncthreads();

    if (t < 64) {                         // wave 0: V_out
        float zp = qb[t] * zb[t];
#pragma unroll
        for (int off = 32; off >= 1; off >>= 1) zp += __shfl_xor(zp, off, 64);
        const float qz = 1.0f / (zp + 1e-6f);
        float vs = 0.0f;
#pragma unroll
        for (int d = 0; d < DDIM; d += 4) {
            const float4 sv = *(const float4*)&S[t * DDIM + d];
            vs = fmaf(qb[d],     sv.x, vs);
            vs = fmaf(qb[d + 1], sv.y, vs);
            vs = fmaf(qb[d + 2], sv.z, vs);
            vs = fmaf(qb[d + 3], sv.w, vs);
        }
        out[(size_t)p * MDIM + t] = qz * vs;
    }
}

// ---------------- fallback: round-1 single-kernel path ----------------
__global__ __launch_bounds__(NTH, 2)
void rcla_single(const float* __restrict__ query,
                 const float* __restrict__ keys,
                 const float* __restrict__ values,
                 const float* __restrict__ kmask,
                 float* __restrict__ out)
{
    __shared__ float Ks[CHUNK * DDIM];
    __shared__ float Vs[CHUNK * MDIM];
    __shared__ float buf[MDIM * DDIM];
    __shared__ float zbuf[DDIM];
    __shared__ float qbuf[DDIM];

    const int t    = threadIdx.x;
    const int pair = blockIdx.x;
    const int nIdx = pair >> 4;
    const int hIdx = pair & 15;
    const int wave = t >> 6;
    const int lane = t & 63;
    const int mgrp = lane >> 3;
    const int dgrp = lane & 7;
    const int m0 = mgrp * 8;
    const int d0 = dgrp * 8;

    const int srow0 = t >> 4;
    const int srow1 = srow0 + 32;
    const int scol  = (t & 15) * 4;

    const size_t rowStride = (size_t)NHEAD * DDIM;
    const size_t base = ((size_t)nIdx * S_LEN * NHEAD + hIdx) * DDIM;
    const float* kp0 = keys   + base + (size_t)srow0 * rowStride + scol;
    const float* kp1 = keys   + base + (size_t)srow1 * rowStride + scol;
    const float* vp0 = values + base + (size_t)srow0 * rowStride + scol;
    const float* vp1 = values + base + (size_t)srow1 * rowStride + scol;
    const float* mp  = kmask + (size_t)nIdx * S_LEN + srow0;

    float acc[8][8];
    float zz[8];
#pragma unroll
    for (int i = 0; i < 8; ++i) {
        zz[i] = 0.0f;
#pragma unroll
        for (int j = 0; j < 8; ++j) acc[i][j] = 0.0f;
    }

    float4 ka = *(const float4*)kp0;
    float4 kb = *(const float4*)kp1;
    float4 va = *(const float4*)vp0;
    float4 vb = *(const float4*)vp1;
    float mk0 = mp[0], mk1 = mp[32];

    const int rbase = wave * 8;
    const size_t step = (size_t)CHUNK * rowStride;

    for (int c = 0; c < S_LEN / CHUNK; ++c) {
        float4 k0, k1;
        k0.x = elup1(ka.x) * mk0;  k0.y = elup1(ka.y) * mk0;
        k0.z = elup1(ka.z) * mk0;  k0.w = elup1(ka.w) * mk0;
        k1.x = elup1(kb.x) * mk1;  k1.y = elup1(kb.y) * mk1;
        k1.z = elup1(kb.z) * mk1;  k1.w = elup1(kb.w) * mk1;
        float4 v0 = va, v1 = vb;

        __syncthreads();
        *(float4*)&Ks[srow0 * DDIM + scol] = k0;
        *(float4*)&Ks[srow1 * DDIM + scol] = k1;
        *(float4*)&Vs[srow0 * MDIM + scol] = v0;
        *(float4*)&Vs[srow1 * MDIM + scol] = v1;
        __syncthreads();

        if (c + 1 < S_LEN / CHUNK) {
            kp0 += step; kp1 += step; vp0 += step; vp1 += step; mp += CHUNK;
            ka = *(const float4*)kp0;
            kb = *(const float4*)kp1;
            va = *(const float4*)vp0;
            vb = *(const float4*)vp1;
            mk0 = mp[0]; mk1 = mp[32];
        }

#pragma unroll
        for (int r = 0; r < 8; ++r) {
            const int row = rbase + r;
            const float4 kk0 = *(const float4*)&Ks[row * DDIM + d0];
            const float4 kk1 = *(const float4*)&Ks[row * DDIM + d0 + 4];
            const float4 vv0 = *(const float4*)&Vs[row * MDIM + m0];
            const float4 vv1 = *(const float4*)&Vs[row * MDIM + m0 + 4];
            const float kv[8] = {kk0.x, kk0.y, kk0.z, kk0.w, kk1.x, kk1.y, kk1.z, kk1.w};
            const float vm[8] = {vv0.x, vv0.y, vv0.z, vv0.w, vv1.x, vv1.y, vv1.z, vv1.w};
#pragma unroll
            for (int mi = 0; mi < 8; ++mi)
#pragma unroll
                for (int di = 0; di < 8; ++di)
                    acc[mi][di] = fmaf(vm[mi], kv[di], acc[mi][di]);
#pragma unroll
            for (int di = 0; di < 8; ++di) zz[di] += kv[di];
        }
    }

    if (t < DDIM) qbuf[t] = elup1(query[(size_t)pair * DDIM + t]);

    for (int w = 0; w < 8; ++w) {
        if (wave == w) {
#pragma unroll
            for (int mi = 0; mi < 8; ++mi) {
                float4* row = (float4*)&buf[(m0 + mi) * DDIM + d0];
                if (w == 0) {
                    row[0] = make_float4(acc[mi][0], acc[mi][1], acc[mi][2], acc[mi][3]);
                    row[1] = make_float4(acc[mi][4], acc[mi][5], acc[mi][6], acc[mi][7]);
                } else {
                    float4 a = row[0], b = row[1];
                    a.x += acc[mi][0]; a.y += acc[mi][1]; a.z += acc[mi][2]; a.w += acc[mi][3];
                    b.x += acc[mi][4]; b.y += acc[mi][5]; b.z += acc[mi][6]; b.w += acc[mi][7];
                    row[0] = a; row[1] = b;
                }
            }
            if (mgrp == 0) {
#pragma unroll
                for (int i = 0; i < 8; ++i) {
                    if (w == 0) zbuf[d0 + i] = zz[i];
                    else        zbuf[d0 + i] += zz[i];
                }
            }
        }
        __syncthreads();
    }

    {
        const int row = t >> 3;
        const int col = (t & 7) * 8;
        float* dst = out + OUT_SOFF + ((size_t)pair * MDIM + row) * DDIM + col;
        *(float4*)dst       = *(float4*)&buf[row * DDIM + col];
        *((float4*)dst + 1) = *(float4*)&buf[row * DDIM + col + 4];
    }

    if (t < DDIM) out[OUT_ZOFF + (size_t)pair * DDIM + t] = zbuf[t];

    if (wave == 0) {
        float q  = qbuf[lane];
        float zp = q * zbuf[lane];
#pragma unroll
        for (int off = 32; off >= 1; off >>= 1) zp += __shfl_xor(zp, off, 64);
        const float qz = 1.0f / (zp + 1e-6f);
        float vs = 0.0f;
#pragma unroll
        for (int d = 0; d < DDIM; d += 4) {
            const float4 sv = *(const float4*)&buf[lane * DDIM + d];
            vs = fmaf(qbuf[d],     sv.x, vs);
            vs = fmaf(qbuf[d + 1], sv.y, vs);
            vs = fmaf(qbuf[d + 2], sv.z, vs);
            vs = fmaf(qbuf[d + 3], sv.w, vs);
        }
        out[(size_t)pair * MDIM + lane] = qz * vs;
    }
}

extern "C" void kernel_launch(void* const* d_in, const int* in_sizes, int n_in,
                              void* d_out, int out_size, void* d_ws, size_t ws_size,
                              hipStream_t stream) {
    const float* q  = (const float*)d_in[0];
    const float* k  = (const float*)d_in[1];
    const float* v  = (const float*)d_in[2];
    const float* km = (const float*)d_in[3];
    float* out = (float*)d_out;

    if (ws_size >= WS_NEED) {
        float* ws = (float*)d_ws;
        rcla_partial<<<dim3(256 * SPLIT), dim3(NTH), 0, stream>>>(k, v, km, ws);
        rcla_reduce<<<dim3(256), dim3(256), 0, stream>>>(q, ws, out);
    } else {
        rcla_single<<<dim3(256), dim3(NTH), 0, stream>>>(q, k, v, km, out);
    }
}

// Round 3
// 169.821 us; speedup vs baseline: 5.6616x; 5.6616x over previous
//
#include <hip/hip_runtime.h>
#include <hip/hip_bf16.h>

// RecurrentCrossLinearAttention: N=16, S=4096, H=16, D=64, M=64, fp32.
// Round 3: split-S (512 blocks = 2/CU) with launch_bounds (512,2) so the
// 8x8 register accumulator is NOT spilled (round-2 bug: (512,4) forced
// VGPR=64 -> scratch spills -> 2.4GB scratch writes, 6x regression).
// Partial S_state/Z -> d_ws; reduce kernel sums halves + epilogue.

#define S_LEN  4096
#define NHEAD  16
#define DDIM   64
#define MDIM   64
#define CHUNK  64
#define NTH    512
#define SPLIT  2
#define SHALF  (S_LEN / SPLIT)
#define NCHUNK_H (SHALF / CHUNK)          // 32 chunks per half

#define OUT_SOFF  16384                   // N*H*M
#define OUT_ZOFF  (16384 + 1048576)       // + N*H*M*D

#define WS_ROW    (MDIM * DDIM + DDIM)    // 4160 floats per partial
#define WS_NEED   ((size_t)256 * SPLIT * WS_ROW * sizeof(float))

__device__ __forceinline__ float elup1(float x) {
    return x > 0.0f ? x + 1.0f : __expf(x);
}

// ---------------- main partial-accumulation kernel (split-S) ----------------
// NOTE: min-waves/EU = 2 (NOT 4): 124 VGPR already allows 16 waves/CU =
// 2 co-resident 512-thread blocks; forcing 4 causes accumulator spill.
__global__ __launch_bounds__(NTH, 2)
void rcla_partial(const float* __restrict__ keys,
                  const float* __restrict__ values,
                  const float* __restrict__ kmask,
                  float* __restrict__ ws)
{
    __shared__ float Ks[CHUNK * DDIM];    // 16 KB (elu'd, masked K)
    __shared__ float Vs[CHUNK * MDIM];    // 16 KB (raw V)
    __shared__ float buf[MDIM * DDIM];    // 16 KB merge buffer
    __shared__ float zbuf[DDIM];

    const int t    = threadIdx.x;
    const int pair = blockIdx.x >> 1;     // n*16 + h
    const int half = blockIdx.x & 1;
    const int nIdx = pair >> 4;
    const int hIdx = pair & 15;
    const int wave = t >> 6;
    const int lane = t & 63;
    const int mgrp = lane >> 3;
    const int dgrp = lane & 7;
    const int m0 = mgrp * 8;
    const int d0 = dgrp * 8;

    const int srow0 = t >> 4;             // 0..31
    const int srow1 = srow0 + 32;
    const int scol  = (t & 15) * 4;

    const size_t rowStride = (size_t)NHEAD * DDIM;   // 1024 floats
    const size_t base = ((size_t)nIdx * S_LEN * NHEAD + hIdx) * DDIM
                      + (size_t)half * SHALF * rowStride;
    const float* kp0 = keys   + base + (size_t)srow0 * rowStride + scol;
    const float* kp1 = keys   + base + (size_t)srow1 * rowStride + scol;
    const float* vp0 = values + base + (size_t)srow0 * rowStride + scol;
    const float* vp1 = values + base + (size_t)srow1 * rowStride + scol;
    const float* mp  = kmask + (size_t)nIdx * S_LEN + half * SHALF + srow0;

    float acc[8][8];
    float zz[8];
#pragma unroll
    for (int i = 0; i < 8; ++i) {
        zz[i] = 0.0f;
#pragma unroll
        for (int j = 0; j < 8; ++j) acc[i][j] = 0.0f;
    }

    float4 ka = *(const float4*)kp0;
    float4 kb = *(const float4*)kp1;
    float4 va = *(const float4*)vp0;
    float4 vb = *(const float4*)vp1;
    float mk0 = mp[0], mk1 = mp[32];

    const int rbase = wave * 8;
    const size_t step = (size_t)CHUNK * rowStride;

    for (int c = 0; c < NCHUNK_H; ++c) {
        float4 k0, k1;
        k0.x = elup1(ka.x) * mk0;  k0.y = elup1(ka.y) * mk0;
        k0.z = elup1(ka.z) * mk0;  k0.w = elup1(ka.w) * mk0;
        k1.x = elup1(kb.x) * mk1;  k1.y = elup1(kb.y) * mk1;
        k1.z = elup1(kb.z) * mk1;  k1.w = elup1(kb.w) * mk1;
        float4 v0 = va, v1 = vb;

        __syncthreads();
        *(float4*)&Ks[srow0 * DDIM + scol] = k0;
        *(float4*)&Ks[srow1 * DDIM + scol] = k1;
        *(float4*)&Vs[srow0 * MDIM + scol] = v0;
        *(float4*)&Vs[srow1 * MDIM + scol] = v1;
        __syncthreads();

        if (c + 1 < NCHUNK_H) {
            kp0 += step; kp1 += step; vp0 += step; vp1 += step; mp += CHUNK;
            ka = *(const float4*)kp0;
            kb = *(const float4*)kp1;
            va = *(const float4*)vp0;
            vb = *(const float4*)vp1;
            mk0 = mp[0]; mk1 = mp[32];
        }

#pragma unroll
        for (int r = 0; r < 8; ++r) {
            const int row = rbase + r;
            const float4 kk0 = *(const float4*)&Ks[row * DDIM + d0];
            const float4 kk1 = *(const float4*)&Ks[row * DDIM + d0 + 4];
            const float4 vv0 = *(const float4*)&Vs[row * MDIM + m0];
            const float4 vv1 = *(const float4*)&Vs[row * MDIM + m0 + 4];
            const float kv[8] = {kk0.x, kk0.y, kk0.z, kk0.w, kk1.x, kk1.y, kk1.z, kk1.w};
            const float vm[8] = {vv0.x, vv0.y, vv0.z, vv0.w, vv1.x, vv1.y, vv1.z, vv1.w};
#pragma unroll
            for (int mi = 0; mi < 8; ++mi)
#pragma unroll
                for (int di = 0; di < 8; ++di)
                    acc[mi][di] = fmaf(vm[mi], kv[di], acc[mi][di]);
#pragma unroll
            for (int di = 0; di < 8; ++di) zz[di] += kv[di];
        }
    }

    // cross-wave merge through LDS
    for (int w = 0; w < 8; ++w) {
        if (wave == w) {
#pragma unroll
            for (int mi = 0; mi < 8; ++mi) {
                float4* row = (float4*)&buf[(m0 + mi) * DDIM + d0];
                if (w == 0) {
                    row[0] = make_float4(acc[mi][0], acc[mi][1], acc[mi][2], acc[mi][3]);
                    row[1] = make_float4(acc[mi][4], acc[mi][5], acc[mi][6], acc[mi][7]);
                } else {
                    float4 a = row[0], b = row[1];
                    a.x += acc[mi][0]; a.y += acc[mi][1]; a.z += acc[mi][2]; a.w += acc[mi][3];
                    b.x += acc[mi][4]; b.y += acc[mi][5]; b.z += acc[mi][6]; b.w += acc[mi][7];
                    row[0] = a; row[1] = b;
                }
            }
            if (mgrp == 0) {
#pragma unroll
                for (int i = 0; i < 8; ++i) {
                    if (w == 0) zbuf[d0 + i] = zz[i];
                    else        zbuf[d0 + i] += zz[i];
                }
            }
        }
        __syncthreads();
    }

    // write partials: [blockIdx.x][4096 S + 64 z]
    float* wrow = ws + (size_t)blockIdx.x * WS_ROW;
    {
        const int row = t >> 3;
        const int col = (t & 7) * 8;
        float* dst = wrow + row * DDIM + col;
        *(float4*)dst       = *(float4*)&buf[row * DDIM + col];
        *((float4*)dst + 1) = *(float4*)&buf[row * DDIM + col + 4];
    }
    if (t < DDIM) wrow[MDIM * DDIM + t] = zbuf[t];
}

// ---------------- reduce + epilogue kernel ----------------
__global__ __launch_bounds__(256)
void rcla_reduce(const float* __restrict__ query,
                 const float* __restrict__ ws,
                 float* __restrict__ out)
{
    __shared__ float S[MDIM * DDIM];
    __shared__ float zb[DDIM];
    __shared__ float qb[DDIM];

    const int p = blockIdx.x;             // pair
    const int t = threadIdx.x;
    const float* a = ws + (size_t)(2 * p) * WS_ROW;
    const float* b = ws + (size_t)(2 * p + 1) * WS_ROW;

    const int i0 = t * 16;
#pragma unroll
    for (int j = 0; j < 16; j += 4) {
        float4 x = *(const float4*)&a[i0 + j];
        const float4 y = *(const float4*)&b[i0 + j];
        x.x += y.x; x.y += y.y; x.z += y.z; x.w += y.w;
        *(float4*)&S[i0 + j] = x;
        *(float4*)&out[OUT_SOFF + (size_t)p * (MDIM * DDIM) + i0 + j] = x;
    }
    if (t < DDIM) {
        const float zv = a[MDIM * DDIM + t] + b[MDIM * DDIM + t];
        zb[t] = zv;
        out[OUT_ZOFF + (size_t)p * DDIM + t] = zv;
        qb[t] = elup1(query[(size_t)p * DDIM + t]);
    }
    __syncthreads();

    if (t < 64) {                         // wave 0: V_out
        float zp = qb[t] * zb[t];
#pragma unroll
        for (int off = 32; off >= 1; off >>= 1) zp += __shfl_xor(zp, off, 64);
        const float qz = 1.0f / (zp + 1e-6f);
        float vs = 0.0f;
#pragma unroll
        for (int d = 0; d < DDIM; d += 4) {
            const float4 sv = *(const float4*)&S[t * DDIM + d];
            vs = fmaf(qb[d],     sv.x, vs);
            vs = fmaf(qb[d + 1], sv.y, vs);
            vs = fmaf(qb[d + 2], sv.z, vs);
            vs = fmaf(qb[d + 3], sv.w, vs);
        }
        out[(size_t)p * MDIM + t] = qz * vs;
    }
}

// ---------------- fallback: round-1 single-kernel path ----------------
__global__ __launch_bounds__(NTH, 2)
void rcla_single(const float* __restrict__ query,
                 const float* __restrict__ keys,
                 const float* __restrict__ values,
                 const float* __restrict__ kmask,
                 float* __restrict__ out)
{
    __shared__ float Ks[CHUNK * DDIM];
    __shared__ float Vs[CHUNK * MDIM];
    __shared__ float buf[MDIM * DDIM];
    __shared__ float zbuf[DDIM];
    __shared__ float qbuf[DDIM];

    const int t    = threadIdx.x;
    const int pair = blockIdx.x;
    const int nIdx = pair >> 4;
    const int hIdx = pair & 15;
    const int wave = t >> 6;
    const int lane = t & 63;
    const int mgrp = lane >> 3;
    const int dgrp = lane & 7;
    const int m0 = mgrp * 8;
    const int d0 = dgrp * 8;

    const int srow0 = t >> 4;
    const int srow1 = srow0 + 32;
    const int scol  = (t & 15) * 4;

    const size_t rowStride = (size_t)NHEAD * DDIM;
    const size_t base = ((size_t)nIdx * S_LEN * NHEAD + hIdx) * DDIM;
    const float* kp0 = keys   + base + (size_t)srow0 * rowStride + scol;
    const float* kp1 = keys   + base + (size_t)srow1 * rowStride + scol;
    const float* vp0 = values + base + (size_t)srow0 * rowStride + scol;
    const float* vp1 = values + base + (size_t)srow1 * rowStride + scol;
    const float* mp  = kmask + (size_t)nIdx * S_LEN + srow0;

    float acc[8][8];
    float zz[8];
#pragma unroll
    for (int i = 0; i < 8; ++i) {
        zz[i] = 0.0f;
#pragma unroll
        for (int j = 0; j < 8; ++j) acc[i][j] = 0.0f;
    }

    float4 ka = *(const float4*)kp0;
    float4 kb = *(const float4*)kp1;
    float4 va = *(const float4*)vp0;
    float4 vb = *(const float4*)vp1;
    float mk0 = mp[0], mk1 = mp[32];

    const int rbase = wave * 8;
    const size_t step = (size_t)CHUNK * rowStride;

    for (int c = 0; c < S_LEN / CHUNK; ++c) {
        float4 k0, k1;
        k0.x = elup1(ka.x) * mk0;  k0.y = elup1(ka.y) * mk0;
        k0.z = elup1(ka.z) * mk0;  k0.w = elup1(ka.w) * mk0;
        k1.x = elup1(kb.x) * mk1;  k1.y = elup1(kb.y) * mk1;
        k1.z = elup1(kb.z) * mk1;  k1.w = elup1(kb.w) * mk1;
        float4 v0 = va, v1 = vb;

        __syncthreads();
        *(float4*)&Ks[srow0 * DDIM + scol] = k0;
        *(float4*)&Ks[srow1 * DDIM + scol] = k1;
        *(float4*)&Vs[srow0 * MDIM + scol] = v0;
        *(float4*)&Vs[srow1 * MDIM + scol] = v1;
        __syncthreads();

        if (c + 1 < S_LEN / CHUNK) {
            kp0 += step; kp1 += step; vp0 += step; vp1 += step; mp += CHUNK;
            ka = *(const float4*)kp0;
            kb = *(const float4*)kp1;
            va = *(const float4*)vp0;
            vb = *(const float4*)vp1;
            mk0 = mp[0]; mk1 = mp[32];
        }

#pragma unroll
        for (int r = 0; r < 8; ++r) {
            const int row = rbase + r;
            const float4 kk0 = *(const float4*)&Ks[row * DDIM + d0];
            const float4 kk1 = *(const float4*)&Ks[row * DDIM + d0 + 4];
            const float4 vv0 = *(const float4*)&Vs[row * MDIM + m0];
            const float4 vv1 = *(const float4*)&Vs[row * MDIM + m0 + 4];
            const float kv[8] = {kk0.x, kk0.y, kk0.z, kk0.w, kk1.x, kk1.y, kk1.z, kk1.w};
            const float vm[8] = {vv0.x, vv0.y, vv0.z, vv0.w, vv1.x, vv1.y, vv1.z, vv1.w};
#pragma unroll
            for (int mi = 0; mi < 8; ++mi)
#pragma unroll
                for (int di = 0; di < 8; ++di)
                    acc[mi][di] = fmaf(vm[mi], kv[di], acc[mi][di]);
#pragma unroll
            for (int di = 0; di < 8; ++di) zz[di] += kv[di];
        }
    }

    if (t < DDIM) qbuf[t] = elup1(query[(size_t)pair * DDIM + t]);

    for (int w = 0; w < 8; ++w) {
        if (wave == w) {
#pragma unroll
            for (int mi = 0; mi < 8; ++mi) {
                float4* row = (float4*)&buf[(m0 + mi) * DDIM + d0];
                if (w == 0) {
                    row[0] = make_float4(acc[mi][0], acc[mi][1], acc[mi][2], acc[mi][3]);
                    row[1] = make_float4(acc[mi][4], acc[mi][5], acc[mi][6], acc[mi][7]);
                } else {
                    float4 a = row[0], b = row[1];
                    a.x += acc[mi][0]; a.y += acc[mi][1]; a.z += acc[mi][2]; a.w += acc[mi][3];
                    b.x += acc[mi][4]; b.y += acc[mi][5]; b.z += acc[mi][6]; b.w += acc[mi][7];
                    row[0] = a; row[1] = b;
                }
            }
            if (mgrp == 0) {
#pragma unroll
                for (int i = 0; i < 8; ++i) {
                    if (w == 0) zbuf[d0 + i] = zz[i];
                    else        zbuf[d0 + i] += zz[i];
                }
            }
        }
        __syncthreads();
    }

    {
        const int row = t >> 3;
        const int col = (t & 7) * 8;
        float* dst = out + OUT_SOFF + ((size_t)pair * MDIM + row) * DDIM + col;
        *(float4*)dst       = *(float4*)&buf[row * DDIM + col];
        *((float4*)dst + 1) = *(float4*)&buf[row * DDIM + col + 4];
    }

    if (t < DDIM) out[OUT_ZOFF + (size_t)pair * DDIM + t] = zbuf[t];

    if (wave == 0) {
        float q  = qbuf[lane];
        float zp = q * zbuf[lane];
#pragma unroll
        for (int off = 32; off >= 1; off >>= 1) zp += __shfl_xor(zp, off, 64);
        const float qz = 1.0f / (zp + 1e-6f);
        float vs = 0.0f;
#pragma unroll
        for (int d = 0; d < DDIM; d += 4) {
            const float4 sv = *(const float4*)&buf[lane * DDIM + d];
            vs = fmaf(qbuf[d],     sv.x, vs);
            vs = fmaf(qbuf[d + 1], sv.y, vs);
            vs = fmaf(qbuf[d + 2], sv.z, vs);
            vs = fmaf(qbuf[d + 3], sv.w, vs);
        }
        out[(size_t)pair * MDIM + lane] = qz * vs;
    }
}

extern "C" void kernel_launch(void* const* d_in, const int* in_sizes, int n_in,
                              void* d_out, int out_size, void* d_ws, size_t ws_size,
                              hipStream_t stream) {
    const float* q  = (const float*)d_in[0];
    const float* k  = (const float*)d_in[1];
    const float* v  = (const float*)d_in[2];
    const float* km = (const float*)d_in[3];
    float* out = (float*)d_out;

    if (ws_size >= WS_NEED) {
        float* ws = (float*)d_ws;
        rcla_partial<<<dim3(256 * SPLIT), dim3(NTH), 0, stream>>>(k, v, km, ws);
        rcla_reduce<<<dim3(256), dim3(256), 0, stream>>>(q, ws, out);
    } else {
        rcla_single<<<dim3(256), dim3(NTH), 0, stream>>>(q, k, v, km, out);
    }
}